// Round 1
// baseline (233.681 us; speedup 1.0000x reference)
//
#include <hip/hip_runtime.h>
#include <cstddef>

// ---------------------------------------------------------------------------
// Problem constants: T=128, B=8, E=1024, H=16, D=64. All GEMMs are 1024^3.
// ---------------------------------------------------------------------------

// C[M,N] = A[M,K] @ B[N,K]^T with M=N=K=1024.
// 64x64 tile, BK=32, 256 threads, each thread a 4x4 micro-tile.
// LDS tiles stored K-major-transposed (As[k][m]) so the inner loop does two
// ds_read_b128 per k-step. Pad 68 keeps float4 alignment + conflict-free banks.
__device__ __forceinline__ void gemm_body(const float* __restrict__ A,
                                          const float* __restrict__ B,
                                          float* __restrict__ C)
{
    __shared__ float As[32][68];
    __shared__ float Bs[32][68];
    const int tid = threadIdx.x;
    const int tx = tid & 15, ty = tid >> 4;
    const int m0 = blockIdx.y << 6, n0 = blockIdx.x << 6;
    float acc[4][4] = {{0.f, 0.f, 0.f, 0.f}};

    for (int k0 = 0; k0 < 1024; k0 += 32) {
#pragma unroll
        for (int r = 0; r < 2; ++r) {
            const int f   = tid + (r << 8);   // 0..511
            const int row = f >> 3;           // 0..63
            const int col = (f & 7) << 2;     // 0..28
            const float4 a = *(const float4*)(A + (size_t)(m0 + row) * 1024 + k0 + col);
            As[col + 0][row] = a.x; As[col + 1][row] = a.y;
            As[col + 2][row] = a.z; As[col + 3][row] = a.w;
            const float4 bb = *(const float4*)(B + (size_t)(n0 + row) * 1024 + k0 + col);
            Bs[col + 0][row] = bb.x; Bs[col + 1][row] = bb.y;
            Bs[col + 2][row] = bb.z; Bs[col + 3][row] = bb.w;
        }
        __syncthreads();
#pragma unroll
        for (int kk = 0; kk < 32; ++kk) {
            const float4 av = *(const float4*)&As[kk][ty << 2];
            const float4 bv = *(const float4*)&Bs[kk][tx << 2];
            const float a4[4] = {av.x, av.y, av.z, av.w};
            const float b4[4] = {bv.x, bv.y, bv.z, bv.w};
#pragma unroll
            for (int i = 0; i < 4; ++i)
#pragma unroll
                for (int j = 0; j < 4; ++j)
                    acc[i][j] = fmaf(a4[i], b4[j], acc[i][j]);
        }
        __syncthreads();
    }
#pragma unroll
    for (int i = 0; i < 4; ++i) {
        const float4 o = make_float4(acc[i][0], acc[i][1], acc[i][2], acc[i][3]);
        *(float4*)(C + (size_t)(m0 + (ty << 2) + i) * 1024 + n0 + (tx << 2)) = o;
    }
}

// Four projections in one launch: z=0..3 -> Q,K,V (from query), R (from rel_pe).
__global__ __launch_bounds__(256) void proj4_kernel(
    const float* __restrict__ query, const float* __restrict__ rel_pe,
    const float* __restrict__ qw, const float* __restrict__ kw,
    const float* __restrict__ vw, const float* __restrict__ rw,
    float* __restrict__ Q, float* __restrict__ K,
    float* __restrict__ V, float* __restrict__ R)
{
    const int z = blockIdx.z;
    const float* A = (z == 3) ? rel_pe : query;
    const float* W = (z == 0) ? qw : (z == 1) ? kw : (z == 2) ? vw : rw;
    float* C = (z == 0) ? Q : (z == 1) ? K : (z == 2) ? V : R;
    gemm_body(A, W, C);
}

__global__ __launch_bounds__(256) void gemm_out_kernel(
    const float* __restrict__ A, const float* __restrict__ W, float* __restrict__ C)
{
    gemm_body(A, W, C);
}

// ---------------------------------------------------------------------------
// Fused attention. Grid = 256 blocks: block bx handles n = bx>>1 (n = b*16+h)
// and query-row half i0 = (bx&1)*64. 256 threads = 4 waves, each wave owns 16
// query rows; within a row, lane l computes scores for j=l and j=l+64.
//
// a1 via LDS (new_q rows + transposed K tile), a2 via precomputed dot0/dot1
// and the utt/spk masks, a3 via the rel-shift identity a3 = c[127 - i + j]
// for j<=i. Mask: score = 1e-30 exactly for j>i (faithful: included in the
// softmax max/sum). PV via shuffle-broadcast of the weights, lane = d.
// ---------------------------------------------------------------------------
__global__ __launch_bounds__(256) void attn_kernel(
    const float* __restrict__ Q, const float* __restrict__ K,
    const float* __restrict__ V, const float* __restrict__ R,
    const float* __restrict__ spk_emb, const int* __restrict__ spk_mask,
    const float* __restrict__ utt_mask, float* __restrict__ ATT)
{
    __shared__ float qs[64][65];     // new_q rows i0..i0+63 (pad 65: dot loop)
    __shared__ float ks_t[64][129];  // ks_t[d][j]  (pad 129: 2-way max reads)
    __shared__ float vs[128][64];    // vs[j][d]
    __shared__ float cbuf[128];      // c[j] = sum_d sq0[d] * r[n,j,d]
    __shared__ float d0buf[64];      // new_q . spk_emb[0]
    __shared__ float d1buf[64];      // new_q . spk_emb[1]
    __shared__ float sq0[64];
    __shared__ float sq1[64];

    const int bx = blockIdx.x;
    const int n = bx >> 1;
    const int half = bx & 1;
    const int b = n >> 4;
    const int h = n & 15;
    const int i0 = half << 6;
    const int tid = threadIdx.x;
    const int colbase = h << 6;

    if (tid < 64) {
        sq0[tid] = spk_emb[colbase + tid];
        sq1[tid] = spk_emb[1024 + colbase + tid];
    }
    __syncthreads();

    // new_q = q + s_q for our 64 rows
    for (int e = tid; e < 64 * 64; e += 256) {
        const int i = e >> 6, d = e & 63;
        qs[i][d] = Q[(size_t)((i0 + i) * 8 + b) * 1024 + colbase + d] + sq0[d];
    }
    // full K (transposed) and V tiles
    for (int e = tid; e < 128 * 64; e += 256) {
        const int j = e >> 6, d = e & 63;
        const size_t gi = (size_t)(j * 8 + b) * 1024 + colbase + d;
        ks_t[d][j] = K[gi];
        vs[j][d]   = V[gi];
    }
    __syncthreads();

    if (tid < 128) {            // c[j]
        float s = 0.f;
#pragma unroll 8
        for (int d = 0; d < 64; ++d)
            s += sq0[d] * R[(size_t)(tid * 8 + b) * 1024 + colbase + d];
        cbuf[tid] = s;
    } else if (tid < 192) {     // dot0/dot1 per local row
        const int i = tid - 128;
        float s0 = 0.f, s1 = 0.f;
#pragma unroll 8
        for (int d = 0; d < 64; ++d) {
            const float qv = qs[i][d];
            s0 = fmaf(qv, sq0[d], s0);
            s1 = fmaf(qv, sq1[d], s1);
        }
        d0buf[i] = s0;
        d1buf[i] = s1;
    }
    __syncthreads();

    const int wave = tid >> 6, lane = tid & 63;
    const int j0 = lane, j1 = lane + 64;

    for (int rr = 0; rr < 16; ++rr) {
        const int il = (wave << 4) + rr;   // local row 0..63
        const int i = i0 + il;             // global row

        float a1a = 0.f, a1b = 0.f;
#pragma unroll 16
        for (int d = 0; d < 64; ++d) {
            const float qv = qs[il][d];
            a1a = fmaf(qv, ks_t[d][j0], a1a);
            a1b = fmaf(qv, ks_t[d][j1], a1b);
        }

        const float du0 = utt_mask[((size_t)n * 128 + i) * 128 + j0];
        const float du1 = utt_mask[((size_t)n * 128 + i) * 128 + j1];
        const int   sm0 = spk_mask[((size_t)b * 128 + i) * 128 + j0];
        const int   sm1 = spk_mask[((size_t)b * 128 + i) * 128 + j1];
        const float dd0 = d0buf[il], dd1 = d1buf[il];

        float s0, s1;
        {
            const float a3 = cbuf[(j0 <= i) ? (127 - i + j0) : 0];
            const float a2 = du0 * (sm0 ? dd1 : dd0);
            const float v = (a1a + a2 + a3) * 0.125f;
            s0 = (j0 > i) ? 1e-30f : v;
        }
        {
            const float a3 = cbuf[(j1 <= i) ? (127 - i + j1) : 0];
            const float a2 = du1 * (sm1 ? dd1 : dd0);
            const float v = (a1b + a2 + a3) * 0.125f;
            s1 = (j1 > i) ? 1e-30f : v;
        }

        // softmax over all 128 values (masked entries participate, faithful)
        float m = fmaxf(s0, s1);
#pragma unroll
        for (int off = 32; off > 0; off >>= 1)
            m = fmaxf(m, __shfl_xor(m, off, 64));
        const float e0 = __expf(s0 - m);
        const float e1 = __expf(s1 - m);
        float sum = e0 + e1;
#pragma unroll
        for (int off = 32; off > 0; off >>= 1)
            sum += __shfl_xor(sum, off, 64);
        const float inv = 1.f / sum;
        const float w0 = e0 * inv, w1 = e1 * inv;

        // PV: lane = d
        float acc = 0.f;
#pragma unroll 8
        for (int j = 0; j < 64; ++j)
            acc = fmaf(__shfl(w0, j, 64), vs[j][lane], acc);
#pragma unroll 8
        for (int j = 0; j < 64; ++j)
            acc = fmaf(__shfl(w1, j, 64), vs[64 + j][lane], acc);

        // ATT row = t*8+b, col = h*64+d  (matches final (T,B,E) flattening)
        ATT[(size_t)(i * 8 + b) * 1024 + colbase + lane] = acc;
    }
}

// ---------------------------------------------------------------------------
extern "C" void kernel_launch(void* const* d_in, const int* in_sizes, int n_in,
                              void* d_out, int out_size, void* d_ws, size_t ws_size,
                              hipStream_t stream)
{
    (void)in_sizes; (void)n_in; (void)out_size; (void)ws_size;

    const float* query  = (const float*)d_in[0];
    // d_in[1] (key) and d_in[2] (value) are unused: reference computes k and v
    // from `query` (faithful to the original module).
    const float* rel_pe = (const float*)d_in[3];
    // d_in[4] attn_mask is the causal mask; reproduced analytically (j > i).
    const float* utt    = (const float*)d_in[5];
    const int*   spk    = (const int*)d_in[6];
    const float* qw     = (const float*)d_in[7];
    const float* kw     = (const float*)d_in[8];
    const float* vw     = (const float*)d_in[9];
    const float* rw     = (const float*)d_in[10];
    const float* spke   = (const float*)d_in[11];
    const float* ow     = (const float*)d_in[12];

    float* Q   = (float*)d_ws;          // 4 MB each, 20 MB total
    float* K   = Q + (1 << 20);
    float* V   = K + (1 << 20);
    float* R   = V + (1 << 20);
    float* ATT = R + (1 << 20);

    proj4_kernel<<<dim3(16, 16, 4), 256, 0, stream>>>(query, rel_pe, qw, kw, vw, rw, Q, K, V, R);
    attn_kernel<<<dim3(256), 256, 0, stream>>>(Q, K, V, R, spke, spk, utt, ATT);
    gemm_out_kernel<<<dim3(16, 16), 256, 0, stream>>>(ATT, ow, (float*)d_out);
}

// Round 2
// 112.151 us; speedup vs baseline: 2.0836x; 2.0836x over previous
//
#include <hip/hip_runtime.h>
#include <hip/hip_bf16.h>
#include <cstddef>
#include <cstdint>

// T=128, B=8, E=1024, H=16, D=64. All GEMMs 1024x1024x1024.
// GEMM path: fp16 inputs (fp16 rounding = 2^-11 keeps final absmax ~6e-4,
// bf16 would be ~4e-3 > 3.0e-3 threshold), fp32 MFMA accumulate.

typedef _Float16 f16;
typedef __attribute__((ext_vector_type(8))) _Float16 f16x8;
typedef __attribute__((ext_vector_type(4))) float f32x4;

#define GLOBAL_TO_LDS(g, l) __builtin_amdgcn_global_load_lds( \
    (const __attribute__((address_space(1))) void*)(g),       \
    (__attribute__((address_space(3))) void*)(l), 16, 0, 0)

// ---------------------------------------------------------------------------
// fp32 -> fp16 conversion: 7 segments of exactly 1M elements each
// (query, rel_pe, qw, kw, vw, rw, ow). grid = (512, 7), 256 thr, 8 elem/thr.
// ---------------------------------------------------------------------------
struct Ptr7 { const float* s[7]; };

__global__ __launch_bounds__(256) void tof16_kernel(Ptr7 p, f16* dbase)
{
    const float* s = p.s[blockIdx.y];
    f16* d = dbase + (size_t)blockIdx.y * (1u << 20);
    const int i = (blockIdx.x * 256 + threadIdx.x) * 8;
    const float4 a = *(const float4*)(s + i);
    const float4 b = *(const float4*)(s + i + 4);
    f16x8 o;
    o[0] = (f16)a.x; o[1] = (f16)a.y; o[2] = (f16)a.z; o[3] = (f16)a.w;
    o[4] = (f16)b.x; o[5] = (f16)b.y; o[6] = (f16)b.z; o[7] = (f16)b.w;
    *(f16x8*)(d + i) = o;
}

// ---------------------------------------------------------------------------
// MFMA GEMM: C[M,N](f32) = A[M,K](f16) @ B[N,K](f16)^T, M=N=1024, K range arg.
// 128x128 tile, BK=64, 256 thr = 4 waves (2x2), wave tile 64x64 = 4x4 frags of
// 16x16x32. Staging via global_load_lds width=16 (linear LDS dest); the XOR
// slot-swizzle (slot ^= row&7) is applied on the GLOBAL source address and
// mirrored on the ds_read side -> conflict-free ds_read_b128 (8 distinct
// bank-quads per 8 lanes). A-frag: row=lane&15, k=(lane>>4)*8+j; B-frag
// symmetric; C/D: col=lane&15, row=(lane>>4)*4+reg (m89-verified layout).
// ---------------------------------------------------------------------------
__device__ __forceinline__ void gemm128(const f16* __restrict__ A,
                                        const f16* __restrict__ B,
                                        float* __restrict__ C,
                                        int kbeg, int kend, int m0, int n0)
{
    __shared__ f16 As[128 * 64];
    __shared__ f16 Bs[128 * 64];
    const int tid = threadIdx.x;
    const int wave = tid >> 6, lane = tid & 63;
    const int wr = wave >> 1, wc = wave & 1;
    const int l16 = lane & 15, lk = lane >> 4;
    f32x4 acc[4][4] = {};

    for (int k0 = kbeg; k0 < kend; k0 += 64) {
#pragma unroll
        for (int it = 0; it < 4; ++it) {
            const int ebase = it * 2048 + wave * 512;      // wave-uniform LDS elem
            const int e = ebase + lane * 8;
            const int row = e >> 6;
            const int slot = (e >> 3) & 7;
            const int scol = ((slot ^ (row & 7)) << 3);    // pre-swizzled source col
            GLOBAL_TO_LDS(A + (size_t)(m0 + row) * 1024 + k0 + scol, As + ebase);
            GLOBAL_TO_LDS(B + (size_t)(n0 + row) * 1024 + k0 + scol, Bs + ebase);
        }
        __syncthreads();   // drains vmcnt + lgkmcnt before compute
#pragma unroll
        for (int ksl = 0; ksl < 2; ++ksl) {
            const int s = ksl * 4 + lk;
            f16x8 af[4], bg[4];
#pragma unroll
            for (int mi = 0; mi < 4; ++mi) {
                const int r = wr * 64 + mi * 16 + l16;
                af[mi] = *(const f16x8*)(As + r * 64 + ((s ^ (r & 7)) << 3));
            }
#pragma unroll
            for (int ni = 0; ni < 4; ++ni) {
                const int r = wc * 64 + ni * 16 + l16;
                bg[ni] = *(const f16x8*)(Bs + r * 64 + ((s ^ (r & 7)) << 3));
            }
#pragma unroll
            for (int mi = 0; mi < 4; ++mi)
#pragma unroll
                for (int ni = 0; ni < 4; ++ni)
                    acc[mi][ni] = __builtin_amdgcn_mfma_f32_16x16x32_f16(
                        af[mi], bg[ni], acc[mi][ni], 0, 0, 0);
        }
        __syncthreads();
    }
#pragma unroll
    for (int mi = 0; mi < 4; ++mi)
#pragma unroll
        for (int ni = 0; ni < 4; ++ni)
#pragma unroll
            for (int r = 0; r < 4; ++r) {
                const int row = m0 + wr * 64 + mi * 16 + lk * 4 + r;
                const int col = n0 + wc * 64 + ni * 16 + l16;
                C[(size_t)row * 1024 + col] = acc[mi][ni][r];
            }
}

// z=0..3 -> Q,K,V (from query_f16), R (from rel_pe_f16). grid (8,8,4) = 256 wg.
__global__ __launch_bounds__(256) void proj4_mfma_kernel(
    const f16* __restrict__ qf, const f16* __restrict__ rf,
    const f16* __restrict__ wbase,
    float* __restrict__ Q, float* __restrict__ K,
    float* __restrict__ V, float* __restrict__ R)
{
    const int z = blockIdx.z;
    const f16* A = (z == 3) ? rf : qf;
    const f16* W = wbase + (size_t)z * (1u << 20);
    float* C = (z == 0) ? Q : (z == 1) ? K : (z == 2) ? V : R;
    gemm128(A, W, C, 0, 1024, blockIdx.y << 7, blockIdx.x << 7);
}

// out projection, split-K2: z=0 -> k[0,512) into P0, z=1 -> k[512,1024) into P1.
__global__ __launch_bounds__(256) void out_mfma_kernel(
    const f16* __restrict__ ATT, const f16* __restrict__ OW,
    float* __restrict__ P0, float* __restrict__ P1)
{
    const int z = blockIdx.z;
    gemm128(ATT, OW, z ? P1 : P0, z * 512, z * 512 + 512,
            blockIdx.y << 7, blockIdx.x << 7);
}

__global__ __launch_bounds__(256) void addreduce_kernel(
    const float* __restrict__ a, const float* __restrict__ b, float* __restrict__ o)
{
    const int i = (blockIdx.x * 256 + threadIdx.x) * 4;
    const float4 x = *(const float4*)(a + i);
    const float4 y = *(const float4*)(b + i);
    *(float4*)(o + i) = make_float4(x.x + y.x, x.y + y.y, x.z + y.z, x.w + y.w);
}

// ---------------------------------------------------------------------------
// Fused attention (unchanged from round 0 except ATT is written as fp16).
// a3 via rel-shift identity a3[i,j] = c[127-i+j] for j<=i; a2 via dot0/dot1 +
// spk/utt masks; masked scores = 1e-30 exactly (participate in softmax).
// ---------------------------------------------------------------------------
__global__ __launch_bounds__(256) void attn_kernel(
    const float* __restrict__ Q, const float* __restrict__ K,
    const float* __restrict__ V, const float* __restrict__ R,
    const float* __restrict__ spk_emb, const int* __restrict__ spk_mask,
    const float* __restrict__ utt_mask, f16* __restrict__ ATT)
{
    __shared__ float qs[64][65];
    __shared__ float ks_t[64][129];
    __shared__ float vs[128][64];
    __shared__ float cbuf[128];
    __shared__ float d0buf[64];
    __shared__ float d1buf[64];
    __shared__ float sq0[64];
    __shared__ float sq1[64];

    const int bx = blockIdx.x;
    const int n = bx >> 1;
    const int half = bx & 1;
    const int b = n >> 4;
    const int h = n & 15;
    const int i0 = half << 6;
    const int tid = threadIdx.x;
    const int colbase = h << 6;

    if (tid < 64) {
        sq0[tid] = spk_emb[colbase + tid];
        sq1[tid] = spk_emb[1024 + colbase + tid];
    }
    __syncthreads();

    for (int e = tid; e < 64 * 64; e += 256) {
        const int i = e >> 6, d = e & 63;
        qs[i][d] = Q[(size_t)((i0 + i) * 8 + b) * 1024 + colbase + d] + sq0[d];
    }
    for (int e = tid; e < 128 * 64; e += 256) {
        const int j = e >> 6, d = e & 63;
        const size_t gi = (size_t)(j * 8 + b) * 1024 + colbase + d;
        ks_t[d][j] = K[gi];
        vs[j][d]   = V[gi];
    }
    __syncthreads();

    if (tid < 128) {
        float s = 0.f;
#pragma unroll 8
        for (int d = 0; d < 64; ++d)
            s += sq0[d] * R[(size_t)(tid * 8 + b) * 1024 + colbase + d];
        cbuf[tid] = s;
    } else if (tid < 192) {
        const int i = tid - 128;
        float s0 = 0.f, s1 = 0.f;
#pragma unroll 8
        for (int d = 0; d < 64; ++d) {
            const float qv = qs[i][d];
            s0 = fmaf(qv, sq0[d], s0);
            s1 = fmaf(qv, sq1[d], s1);
        }
        d0buf[i] = s0;
        d1buf[i] = s1;
    }
    __syncthreads();

    const int wave = tid >> 6, lane = tid & 63;
    const int j0 = lane, j1 = lane + 64;

    for (int rr = 0; rr < 16; ++rr) {
        const int il = (wave << 4) + rr;
        const int i = i0 + il;

        float a1a = 0.f, a1b = 0.f;
#pragma unroll 16
        for (int d = 0; d < 64; ++d) {
            const float qv = qs[il][d];
            a1a = fmaf(qv, ks_t[d][j0], a1a);
            a1b = fmaf(qv, ks_t[d][j1], a1b);
        }

        const float du0 = utt_mask[((size_t)n * 128 + i) * 128 + j0];
        const float du1 = utt_mask[((size_t)n * 128 + i) * 128 + j1];
        const int   sm0 = spk_mask[((size_t)b * 128 + i) * 128 + j0];
        const int   sm1 = spk_mask[((size_t)b * 128 + i) * 128 + j1];
        const float dd0 = d0buf[il], dd1 = d1buf[il];

        float s0, s1;
        {
            const float a3 = cbuf[(j0 <= i) ? (127 - i + j0) : 0];
            const float a2 = du0 * (sm0 ? dd1 : dd0);
            const float v = (a1a + a2 + a3) * 0.125f;
            s0 = (j0 > i) ? 1e-30f : v;
        }
        {
            const float a3 = cbuf[(j1 <= i) ? (127 - i + j1) : 0];
            const float a2 = du1 * (sm1 ? dd1 : dd0);
            const float v = (a1b + a2 + a3) * 0.125f;
            s1 = (j1 > i) ? 1e-30f : v;
        }

        float m = fmaxf(s0, s1);
#pragma unroll
        for (int off = 32; off > 0; off >>= 1)
            m = fmaxf(m, __shfl_xor(m, off, 64));
        const float e0 = __expf(s0 - m);
        const float e1 = __expf(s1 - m);
        float sum = e0 + e1;
#pragma unroll
        for (int off = 32; off > 0; off >>= 1)
            sum += __shfl_xor(sum, off, 64);
        const float inv = 1.f / sum;
        const float w0 = e0 * inv, w1 = e1 * inv;

        float acc = 0.f;
#pragma unroll 8
        for (int j = 0; j < 64; ++j)
            acc = fmaf(__shfl(w0, j, 64), vs[j][lane], acc);
#pragma unroll 8
        for (int j = 0; j < 64; ++j)
            acc = fmaf(__shfl(w1, j, 64), vs[64 + j][lane], acc);

        ATT[(size_t)(i * 8 + b) * 1024 + colbase + lane] = (f16)acc;
    }
}

// ---------------------------------------------------------------------------
extern "C" void kernel_launch(void* const* d_in, const int* in_sizes, int n_in,
                              void* d_out, int out_size, void* d_ws, size_t ws_size,
                              hipStream_t stream)
{
    (void)in_sizes; (void)n_in; (void)out_size; (void)ws_size;

    const float* query  = (const float*)d_in[0];
    // d_in[1] (key), d_in[2] (value) unused: reference derives k,v from query.
    const float* rel_pe = (const float*)d_in[3];
    // d_in[4] attn_mask: causal, reproduced analytically (j > i).
    const float* utt    = (const float*)d_in[5];
    const int*   spk    = (const int*)d_in[6];
    const float* qw     = (const float*)d_in[7];
    const float* kw     = (const float*)d_in[8];
    const float* vw     = (const float*)d_in[9];
    const float* rw     = (const float*)d_in[10];
    const float* spke   = (const float*)d_in[11];
    const float* ow     = (const float*)d_in[12];

    // workspace layout (40 MB total)
    char* ws = (char*)d_ws;
    float* Q   = (float*)(ws + 0);              // 4 MB
    float* Kp  = (float*)(ws + (4u  << 20));    // 4 MB
    float* Vp  = (float*)(ws + (8u  << 20));    // 4 MB
    float* Rp  = (float*)(ws + (12u << 20));    // 4 MB
    f16*   ATT = (f16*)  (ws + (16u << 20));    // 2 MB
    f16*   fb  = (f16*)  (ws + (18u << 20));    // 7 x 2 MB f16 buffers
    float* P0  = (float*)(ws + (32u << 20));    // 4 MB
    float* P1  = (float*)(ws + (36u << 20));    // 4 MB

    f16* qf = fb;                       // z=0
    f16* rf = fb + (1u << 20);          // z=1
    f16* wb = fb + (2u << 20);          // z=2..5: qw,kw,vw,rw
    f16* ob = fb + (6u << 20);          // z=6: ow

    Ptr7 p7;
    p7.s[0] = query; p7.s[1] = rel_pe; p7.s[2] = qw; p7.s[3] = kw;
    p7.s[4] = vw; p7.s[5] = rw; p7.s[6] = ow;

    tof16_kernel<<<dim3(512, 7), 256, 0, stream>>>(p7, fb);
    proj4_mfma_kernel<<<dim3(8, 8, 4), 256, 0, stream>>>(qf, rf, wb, Q, Kp, Vp, Rp);
    attn_kernel<<<dim3(256), 256, 0, stream>>>(Q, Kp, Vp, Rp, spke, spk, utt, ATT);
    out_mfma_kernel<<<dim3(8, 8, 2), 256, 0, stream>>>(ATT, ob, P0, P1);
    addreduce_kernel<<<dim3(1024), 256, 0, stream>>>(P0, P1, (float*)d_out);
}

// Round 3
// 70.500 us; speedup vs baseline: 3.3146x; 1.5908x over previous
//
#include <hip/hip_runtime.h>
#include <hip/hip_bf16.h>
#include <cstddef>
#include <cstdint>

// T=128, B=8, E=1024, H=16, D=64. GEMMs 1024^3. fp16 inputs, fp32 MFMA acc.

typedef _Float16 f16;
typedef __attribute__((ext_vector_type(8))) _Float16 f16x8;
typedef __attribute__((ext_vector_type(4))) float f32x4;

#define GLOBAL_TO_LDS(g, l) __builtin_amdgcn_global_load_lds( \
    (const __attribute__((address_space(1))) void*)(g),       \
    (__attribute__((address_space(3))) void*)(l), 16, 0, 0)

// ---------------------------------------------------------------------------
// fp32 -> fp16: 7 segments of 1M elems (query, rel_pe, qw, kw, vw, rw, ow).
// ---------------------------------------------------------------------------
struct Ptr7 { const float* s[7]; };

__global__ __launch_bounds__(256) void tof16_kernel(Ptr7 p, f16* dbase)
{
    const float* s = p.s[blockIdx.y];
    f16* d = dbase + (size_t)blockIdx.y * (1u << 20);
    const int i = (blockIdx.x * 256 + threadIdx.x) * 8;
    const float4 a = *(const float4*)(s + i);
    const float4 b = *(const float4*)(s + i + 4);
    f16x8 o;
    o[0] = (f16)a.x; o[1] = (f16)a.y; o[2] = (f16)a.z; o[3] = (f16)a.w;
    o[4] = (f16)b.x; o[5] = (f16)b.y; o[6] = (f16)b.z; o[7] = (f16)b.w;
    *(f16x8*)(d + i) = o;
}

// ---------------------------------------------------------------------------
// MFMA GEMM, 128x128 tile, BK=64, 4 waves (2x2), templated epilogue.
// C[m][n] = sum_k A[m][k] * B[n][k]. Swizzle: slot ^= row&7 (16B slots),
// applied on the global source (global_load_lds writes linearly) and
// mirrored on the ds_read side.
// ---------------------------------------------------------------------------
template <class Epi>
__device__ __forceinline__ void gemm128(const f16* __restrict__ A,
                                        const f16* __restrict__ B,
                                        int kbeg, int kend, int m0, int n0,
                                        Epi epi)
{
    __shared__ f16 As[128 * 64];
    __shared__ f16 Bs[128 * 64];
    const int tid = threadIdx.x;
    const int wave = tid >> 6, lane = tid & 63;
    const int wr = wave >> 1, wc = wave & 1;
    const int l16 = lane & 15, lk = lane >> 4;
    f32x4 acc[4][4] = {};

    for (int k0 = kbeg; k0 < kend; k0 += 64) {
#pragma unroll
        for (int it = 0; it < 4; ++it) {
            const int ebase = it * 2048 + wave * 512;
            const int e = ebase + lane * 8;
            const int row = e >> 6;
            const int slot = (e >> 3) & 7;
            const int scol = (slot ^ (row & 7)) << 3;
            GLOBAL_TO_LDS(A + (size_t)(m0 + row) * 1024 + k0 + scol, As + ebase);
            GLOBAL_TO_LDS(B + (size_t)(n0 + row) * 1024 + k0 + scol, Bs + ebase);
        }
        __syncthreads();
#pragma unroll
        for (int ksl = 0; ksl < 2; ++ksl) {
            const int s = ksl * 4 + lk;
            f16x8 af[4], bg[4];
#pragma unroll
            for (int mi = 0; mi < 4; ++mi) {
                const int r = wr * 64 + mi * 16 + l16;
                af[mi] = *(const f16x8*)(As + r * 64 + ((s ^ (r & 7)) << 3));
            }
#pragma unroll
            for (int ni = 0; ni < 4; ++ni) {
                const int r = wc * 64 + ni * 16 + l16;
                bg[ni] = *(const f16x8*)(Bs + r * 64 + ((s ^ (r & 7)) << 3));
            }
#pragma unroll
            for (int mi = 0; mi < 4; ++mi)
#pragma unroll
                for (int ni = 0; ni < 4; ++ni)
                    acc[mi][ni] = __builtin_amdgcn_mfma_f32_16x16x32_f16(
                        af[mi], bg[ni], acc[mi][ni], 0, 0, 0);
        }
        __syncthreads();
    }
#pragma unroll
    for (int mi = 0; mi < 4; ++mi)
#pragma unroll
        for (int ni = 0; ni < 4; ++ni)
#pragma unroll
            for (int r = 0; r < 4; ++r)
                epi(m0 + wr * 64 + mi * 16 + lk * 4 + r,
                    n0 + wc * 64 + ni * 16 + l16, acc[mi][ni][r]);
}

// Head-major f16 epilogue: dst[n=(row&7)*16+(col>>6)][t=row>>3][d=col&63].
// addvec (spk_emb row 0) folded in for the Q projection -> stores new_q.
struct EpiHead {
    f16* dst; const float* addvec;
    __device__ void operator()(int row, int col, float v) const {
        const float x = addvec ? v + addvec[col] : v;
        const int b = row & 7, t = row >> 3, h = col >> 6, d = col & 63;
        dst[(size_t)(((b << 4) + h) * 128 + t) * 64 + d] = (f16)x;
    }
};
struct EpiF32 {
    float* dst;
    __device__ void operator()(int row, int col, float v) const {
        dst[(size_t)row * 1024 + col] = v;
    }
};

__global__ __launch_bounds__(256) void proj4_mfma_kernel(
    const f16* __restrict__ qf, const f16* __restrict__ rf,
    const f16* __restrict__ wbase, const float* __restrict__ spk_emb,
    f16* __restrict__ Qh, f16* __restrict__ Kh,
    f16* __restrict__ Vh, f16* __restrict__ Rh)
{
    const int z = blockIdx.z;
    const f16* A = (z == 3) ? rf : qf;
    const f16* W = wbase + ((size_t)z << 20);
    f16* dst = (z == 0) ? Qh : (z == 1) ? Kh : (z == 2) ? Vh : Rh;
    EpiHead epi{dst, (z == 0) ? spk_emb : nullptr};
    gemm128(A, W, 0, 1024, blockIdx.y << 7, blockIdx.x << 7, epi);
}

__global__ __launch_bounds__(256) void out_mfma_kernel(
    const f16* __restrict__ ATT, const f16* __restrict__ OW,
    float* __restrict__ P0, float* __restrict__ P1)
{
    const int z = blockIdx.z;
    EpiF32 epi{z ? P1 : P0};
    gemm128(ATT, OW, z * 512, z * 512 + 512, blockIdx.y << 7, blockIdx.x << 7, epi);
}

__global__ __launch_bounds__(256) void addreduce_kernel(
    const float* __restrict__ a, const float* __restrict__ b, float* __restrict__ o)
{
    const int i = (blockIdx.x * 256 + threadIdx.x) * 4;
    const float4 x = *(const float4*)(a + i);
    const float4 y = *(const float4*)(b + i);
    *(float4*)(o + i) = make_float4(x.x + y.x, x.y + y.y, x.z + y.z, x.w + y.w);
}

// ---------------------------------------------------------------------------
// MFMA attention. Block = (n, half): 64 q-rows; 4 waves x 16 rows.
// QK^T: A=newQ(LDS), B=K(LDS). PV: A=P(per-wave LDS), B=V^T(LDS transpose).
// a2 = utt * (spk ? dot1 : dot0); a3 = c[127-i+j] (j<=i); masked score=1e-30.
// All LDS tiles XOR-swizzled (slot ^= row&7 on 16B slots).
// ---------------------------------------------------------------------------
__global__ __launch_bounds__(256) void attn_mfma_kernel(
    const f16* __restrict__ Qh, const f16* __restrict__ Kh,
    const f16* __restrict__ Vh, const f16* __restrict__ Rh,
    const float* __restrict__ spk_emb, const int* __restrict__ spk_mask,
    const float* __restrict__ utt_mask, f16* __restrict__ ATT)
{
    __shared__ __attribute__((aligned(16))) char smem[58880];
    f16* nq = (f16*)smem;                  // [64][64]  swz   8192B
    f16* kt = (f16*)(smem + 8192);         // [128][64] swz  16384B
    f16* vt = (f16*)(smem + 24576);        // [64][128] swz  16384B
    f16* vs = (f16*)(smem + 40960);        // [128][64] swz stage; reused as P
    float* cbuf = (float*)(smem + 57344);  // 128 f32
    float* dd   = (float*)(smem + 57856);  // dot0[64], dot1[64]
    float* sq   = (float*)(smem + 58368);  // sq0[64], sq1[64]

    const int bx = blockIdx.x, n = bx >> 1, half = bx & 1;
    const int b = n >> 4, h = n & 15, i0 = half << 6;
    const int tid = threadIdx.x, wave = tid >> 6, lane = tid & 63;
    const int l16 = lane & 15, lk = lane >> 4;
    const size_t hb = (size_t)n * (128 * 64);

    if (tid < 128)
        sq[tid] = spk_emb[(tid >> 6) * 1024 + (h << 6) + (tid & 63)];

    // stage newQ (64x64), K (128x64), V (128x64) with pre-swizzled source
#pragma unroll
    for (int it = 0; it < 2; ++it) {
        const int ebase = it * 2048 + wave * 512;
        const int e = ebase + lane * 8;
        const int row = e >> 6, slot = (e >> 3) & 7;
        const int scol = (slot ^ (row & 7)) << 3;
        GLOBAL_TO_LDS(Qh + hb + (size_t)(i0 + row) * 64 + scol, nq + ebase);
    }
#pragma unroll
    for (int it = 0; it < 4; ++it) {
        const int ebase = it * 2048 + wave * 512;
        const int e = ebase + lane * 8;
        const int row = e >> 6, slot = (e >> 3) & 7;
        const int scol = (slot ^ (row & 7)) << 3;
        GLOBAL_TO_LDS(Kh + hb + (size_t)row * 64 + scol, kt + ebase);
        GLOBAL_TO_LDS(Vh + hb + (size_t)row * 64 + scol, vs + ebase);
    }
    __syncthreads();

    // transpose V: vt[d][j] = V[j][d] (reads complete before 2nd barrier)
#pragma unroll
    for (int dc = 0; dc < 2; ++dc) {
        const int dchunk = wave * 2 + dc;      // 0..7
#pragma unroll
        for (int jg = 0; jg < 2; ++jg) {
            const int j = jg * 64 + lane;
            const f16x8 v = *(const f16x8*)(vs + j * 64 + ((dchunk ^ (j & 7)) << 3));
#pragma unroll
            for (int e = 0; e < 8; ++e) {
                const int d = dchunk * 8 + e;
                vt[d * 128 + ((((j >> 3) ^ (d & 7)) << 3) | (j & 7))] = v[e];
            }
        }
    }

    if (tid < 128) {                 // c[j] = sum_d sq0[d] * R[n][j][d]
        const int j = tid;
        float s = 0.f;
#pragma unroll
        for (int c = 0; c < 8; ++c) {
            const f16x8 rv = *(const f16x8*)(Rh + hb + (size_t)j * 64 + c * 8);
#pragma unroll
            for (int e = 0; e < 8; ++e)
                s = fmaf((float)rv[e], sq[c * 8 + e], s);
        }
        cbuf[j] = s;
    } else if (tid < 192) {          // dot0/dot1 per local row (newQ incl s_q)
        const int i = tid - 128;
        float s0 = 0.f, s1 = 0.f;
#pragma unroll
        for (int c = 0; c < 8; ++c) {
            const f16x8 qv = *(const f16x8*)(nq + i * 64 + ((c ^ (i & 7)) << 3));
#pragma unroll
            for (int e = 0; e < 8; ++e) {
                const float q = (float)qv[e];
                s0 = fmaf(q, sq[c * 8 + e], s0);
                s1 = fmaf(q, sq[64 + c * 8 + e], s1);
            }
        }
        dd[i] = s0; dd[64 + i] = s1;
    }
    __syncthreads();

    // ---- QK^T: per-wave M=16 rows, N=128, K=64 -> 16 MFMAs
    const int iw = wave * 16 + l16;
    f16x8 af[2];
#pragma unroll
    for (int ksl = 0; ksl < 2; ++ksl) {
        const int s = ksl * 4 + lk;
        af[ksl] = *(const f16x8*)(nq + iw * 64 + ((s ^ (iw & 7)) << 3));
    }
    f32x4 sacc[8] = {};
#pragma unroll
    for (int ksl = 0; ksl < 2; ++ksl) {
        const int s = ksl * 4 + lk;
#pragma unroll
        for (int ni = 0; ni < 8; ++ni) {
            const int j = ni * 16 + l16;
            const f16x8 bg = *(const f16x8*)(kt + j * 64 + ((s ^ (j & 7)) << 3));
            sacc[ni] = __builtin_amdgcn_mfma_f32_16x16x32_f16(af[ksl], bg, sacc[ni], 0, 0, 0);
        }
    }

    // ---- scores + softmax (lane holds rows lk*4+r, cols ni*16+l16)
    const int il0 = wave * 16 + lk * 4;     // local row base (+r)
    float sc[8][4];
#pragma unroll
    for (int ni = 0; ni < 8; ++ni) {
        const int j = ni * 16 + l16;
#pragma unroll
        for (int r = 0; r < 4; ++r) {
            const int il = il0 + r, i = i0 + il;
            const float du = utt_mask[((size_t)n * 128 + i) * 128 + j];
            const int   sm = spk_mask[((size_t)b * 128 + i) * 128 + j];
            const float a2 = du * (sm ? dd[64 + il] : dd[il]);
            const float a3 = (j <= i) ? cbuf[127 - i + j] : 0.f;
            const float v = (sacc[ni][r] + a2 + a3) * 0.125f;
            sc[ni][r] = (j > i) ? 1e-30f : v;
        }
    }
    float inv[4];
    f16* ps = vs + wave * 2048;             // per-wave P tile [16][128] swz
#pragma unroll
    for (int r = 0; r < 4; ++r) {
        float m = sc[0][r];
#pragma unroll
        for (int ni = 1; ni < 8; ++ni) m = fmaxf(m, sc[ni][r]);
#pragma unroll
        for (int off = 8; off > 0; off >>= 1) m = fmaxf(m, __shfl_xor(m, off, 64));
        float ssum = 0.f;
#pragma unroll
        for (int ni = 0; ni < 8; ++ni) {
            const float e = __expf(sc[ni][r] - m);
            sc[ni][r] = e;
            ssum += e;
        }
#pragma unroll
        for (int off = 8; off > 0; off >>= 1) ssum += __shfl_xor(ssum, off, 64);
        inv[r] = 1.f / ssum;
    }
#pragma unroll
    for (int ni = 0; ni < 8; ++ni) {
        const int j = ni * 16 + l16;
#pragma unroll
        for (int r = 0; r < 4; ++r) {
            const int il = lk * 4 + r;      // row within wave tile
            ps[il * 128 + ((((j >> 3) ^ (il & 7)) << 3) | (j & 7))] = (f16)sc[ni][r];
        }
    }

    // ---- PV: M=16, N=64, K=128 -> 16 MFMAs
    f16x8 pa[4];
#pragma unroll
    for (int ks = 0; ks < 4; ++ks) {
        const int slot = ks * 4 + lk;
        pa[ks] = *(const f16x8*)(ps + l16 * 128 + ((slot ^ (l16 & 7)) << 3));
    }
    f32x4 oacc[4] = {};
#pragma unroll
    for (int ks = 0; ks < 4; ++ks) {
        const int slot = ks * 4 + lk;
#pragma unroll
        for (int nd = 0; nd < 4; ++nd) {
            const int d = nd * 16 + l16;
            const f16x8 vb = *(const f16x8*)(vt + d * 128 + ((slot ^ (d & 7)) << 3));
            oacc[nd] = __builtin_amdgcn_mfma_f32_16x16x32_f16(pa[ks], vb, oacc[nd], 0, 0, 0);
        }
    }
#pragma unroll
    for (int nd = 0; nd < 4; ++nd)
#pragma unroll
        for (int r = 0; r < 4; ++r) {
            const int i = i0 + il0 + r;
            const int col = (h << 6) + nd * 16 + l16;
            ATT[(size_t)(i * 8 + b) * 1024 + col] = (f16)(oacc[nd][r] * inv[r]);
        }
}

// ---------------------------------------------------------------------------
extern "C" void kernel_launch(void* const* d_in, const int* in_sizes, int n_in,
                              void* d_out, int out_size, void* d_ws, size_t ws_size,
                              hipStream_t stream)
{
    (void)in_sizes; (void)n_in; (void)out_size; (void)ws_size;

    const float* query  = (const float*)d_in[0];
    // d_in[1] (key), d_in[2] (value) unused: reference derives k,v from query.
    const float* rel_pe = (const float*)d_in[3];
    // d_in[4] attn_mask: causal, reproduced analytically (j > i).
    const float* utt    = (const float*)d_in[5];
    const int*   spk    = (const int*)d_in[6];
    const float* qw     = (const float*)d_in[7];
    const float* kw     = (const float*)d_in[8];
    const float* vw     = (const float*)d_in[9];
    const float* rw     = (const float*)d_in[10];
    const float* spke   = (const float*)d_in[11];
    const float* ow     = (const float*)d_in[12];

    char* ws = (char*)d_ws;
    f16* Qh  = (f16*)(ws);                 // 2 MB each, head-major [n][t][d]
    f16* Kh  = (f16*)(ws + (2u  << 20));
    f16* Vh  = (f16*)(ws + (4u  << 20));
    f16* Rh  = (f16*)(ws + (6u  << 20));
    f16* ATT = (f16*)(ws + (8u  << 20));   // 2 MB, [t*8+b][e]
    f16* fb  = (f16*)(ws + (10u << 20));   // 7 x 2 MB f16 conversions
    float* P0 = (float*)(ws + (24u << 20));
    float* P1 = (float*)(ws + (28u << 20));

    f16* qf = fb;
    f16* rf = fb + (1u << 20);
    f16* wb = fb + (2u << 20);             // qw,kw,vw,rw
    f16* ob = fb + (6u << 20);             // ow

    Ptr7 p7;
    p7.s[0] = query; p7.s[1] = rel_pe; p7.s[2] = qw; p7.s[3] = kw;
    p7.s[4] = vw; p7.s[5] = rw; p7.s[6] = ow;

    tof16_kernel<<<dim3(512, 7), 256, 0, stream>>>(p7, fb);
    proj4_mfma_kernel<<<dim3(8, 8, 4), 256, 0, stream>>>(qf, rf, wb, spke, Qh, Kh, Vh, Rh);
    attn_mfma_kernel<<<dim3(256), 256, 0, stream>>>(Qh, Kh, Vh, Rh, spke, spk, utt, ATT);
    out_mfma_kernel<<<dim3(8, 8, 2), 256, 0, stream>>>(ATT, ob, P0, P1);
    addreduce_kernel<<<dim3(1024), 256, 0, stream>>>(P0, P1, (float*)d_out);
}